// Round 8
// baseline (420.330 us; speedup 1.0000x reference)
//
#include <hip/hip_runtime.h>
#include <math.h>

__device__ __forceinline__ float rho(float s) { return fminf(fmaxf(s, 0.f), 1.f); }
// d/ds clip(s,0,1) with JAX maximum/minimum tie-gradient = 0.5
__device__ __forceinline__ float drho(float s) {
  if (s < 0.f || s > 1.f) return 0.f;
  float g = 1.f;
  if (s == 0.f) g *= 0.5f;
  if (s == 1.f) g *= 0.5f;
  return g;
}

// v += CTRL-shifted v within 16-lane DPP row; bound_ctrl -> 0 fill.
// row_shr moves data toward HIGHER lanes: after shr 8,4,2,1 the complete
// 16-sum is in lane (row%16)==15 (AMD cross-lane reduction idiom; r7 bug).
template <int CTRL>
__device__ __forceinline__ float dpp_add(float v) {
  const int x =
      __builtin_amdgcn_update_dpp(0, __float_as_int(v), CTRL, 0xf, 0xf, true);
  return v + __int_as_float(x);
}
__device__ __forceinline__ float dpp_reduce16(float v) {
  v = dpp_add<0x118>(v);  // row_shr:8
  v = dpp_add<0x114>(v);  // row_shr:4
  v = dpp_add<0x112>(v);  // row_shr:2
  v = dpp_add<0x111>(v);  // row_shr:1  -> lane rr==15 holds the 16-sum
  return v;
}

// ---------------- Phase A: per-block partials of c0 = rho(x) @ W0 ----------
template <int ROWS>
__global__ __launch_bounds__(256) void k1_xw0(const float* __restrict__ x,
                                              const float* __restrict__ W0,
                                              float* __restrict__ part) {
  __shared__ float xs[ROWS];
  __shared__ float red[8][132];
  const int t = threadIdx.x;
  const int b = blockIdx.x;
  const int r0 = b * ROWS;
  for (int i = t; i < ROWS; i += 256) xs[i] = rho(x[r0 + i]);
  __syncthreads();
  const int cq = t & 31;
  const int rg = t >> 5;
  constexpr int GR = ROWS / 8;
  const float4* __restrict__ W4 = reinterpret_cast<const float4*>(W0);
  float ax = 0.f, ay = 0.f, az = 0.f, aw = 0.f;
  const int base = (r0 + rg * GR) * 32 + cq;
#pragma unroll 8
  for (int i = 0; i < GR; ++i) {
    const float xv = xs[rg * GR + i];
    const float4 w = W4[base + i * 32];
    ax = fmaf(xv, w.x, ax);
    ay = fmaf(xv, w.y, ay);
    az = fmaf(xv, w.z, az);
    aw = fmaf(xv, w.w, aw);
  }
  red[rg][cq * 4 + 0] = ax;
  red[rg][cq * 4 + 1] = ay;
  red[rg][cq * 4 + 2] = az;
  red[rg][cq * 4 + 3] = aw;
  __syncthreads();
  if (t < 128) {
    float s = 0.f;
#pragma unroll
    for (int g = 0; g < 8; ++g) s += red[g][t];
    part[b * 128 + t] = s;
  }
}

// ---------------- Phase A2: tree-reduce part1 (nblk x 128) -> part2 --------
__global__ __launch_bounds__(256) void k1b_reduce(const float* __restrict__ part1,
                                                  float* __restrict__ part2) {
  __shared__ float acc[2][128];
  const int t = threadIdx.x, i = blockIdx.x;
  const int jk = t & 127, half = t >> 7;
  float s = 0.f;
  const int r0 = i * 32 + half * 16;
#pragma unroll
  for (int r = 0; r < 16; ++r) s += part1[(r0 + r) * 128 + jk];
  acc[half][jk] = s;
  __syncthreads();
  if (half == 0) part2[i * 128 + jk] = acc[0][jk] + acc[1][jk];
}

// ---------------- Phase B: ONE workgroup, W1 resident on a single CU --------
// 512 threads = 8 waves. Thread (rr, cg): rr = lane&15 (8 rows), cg = wave*4 +
// (lane>>4) (col group): 24 reg cols [24cg..) of [0,768) + 8 LDS cols
// 768+[8cg..). Per iter: ONE fused pass over W1 computes both b = W1^T rh and
// a-partials pa = W1 ro; b reduced via DPP row_shr (VALU), a staged via LDS.
// No inter-block traffic at all: 2 __syncthreads per iteration.
__global__ __launch_bounds__(512, 2) void k2_iter(const float* __restrict__ part2,
                                                  const int npart2,
                                                  const float* __restrict__ W1,
                                                  const float* __restrict__ b1,
                                                  const float* __restrict__ b2,
                                                  const int* __restrict__ niterp,
                                                  float* __restrict__ out) {
  __shared__ float wlds[256 * 128];  // 128 KB: cols 768..1023, swizzled
  __shared__ float ro_[1024];
  __shared__ float rh_[128];
  __shared__ float bl_[1024];
  __shared__ float ap_[32][132];     // a-partials per col-group

  const int t = threadIdx.x;
  const int lane = t & 63;
  const int wv = t >> 6;
  const int rr = lane & 15;        // row group: rows [8rr, 8rr+8)
  const int cg = wv * 4 + (lane >> 4);  // col group in [0,32)
  const int RC = cg * 24;          // reg-col base (global col)
  const int LC = 768 + cg * 8;     // lds-col base (global col)

  // ---- load reg tile W[8rr..+8][RC..RC+24) : 192 VGPRs, static-indexed ----
  float w[192];
#pragma unroll
  for (int r = 0; r < 8; ++r) {
    const float4* gr =
        reinterpret_cast<const float4*>(W1 + (8 * rr + r) * 1024 + RC);
#pragma unroll
    for (int i = 0; i < 6; ++i) {
      const float4 v = gr[i];
      w[r * 24 + 4 * i + 0] = v.x;
      w[r * 24 + 4 * i + 1] = v.y;
      w[r * 24 + 4 * i + 2] = v.z;
      w[r * 24 + 4 * i + 3] = v.w;
    }
  }
  // ---- load cols 768..1023 into LDS, slot-permuted + row4-XOR swizzled ----
  // col k (local [0,256)) -> slot s = (k&7)*32 + (k>>3); element (j,k) at
  // wlds[s*128 + ((j>>2 ^ (s&7))<<2) + (j&3)]  (conflict-free tile reads)
  {
    const int j = t >> 2;
    const int kb = (t & 3) * 64;
#pragma unroll
    for (int i = 0; i < 16; ++i) {
      const float4 v =
          *reinterpret_cast<const float4*>(W1 + j * 1024 + 768 + kb + 4 * i);
#pragma unroll
      for (int q = 0; q < 4; ++q) {
        const int K = kb + 4 * i + q;
        const int s = (K & 7) * 32 + (K >> 3);
        wlds[s * 128 + (((j >> 2) ^ (s & 7)) << 2) + (j & 3)] = (&v.x)[q];
      }
    }
  }
  // ---- init: c0 (rows, t<128), biases, zero state ----
  float c0v = 0.f, b1v = 0.f, hreg = 0.f, mh = 0.f, vh = 0.f;
  if (t < 128) {
    float s0 = 0.f, s1 = 0.f, s2 = 0.f, s3 = 0.f;
    for (int r = 0; r < npart2; r += 4) {
      s0 += part2[(r + 0) * 128 + t];
      s1 += part2[(r + 1) * 128 + t];
      s2 += part2[(r + 2) * 128 + t];
      s3 += part2[(r + 3) * 128 + t];
    }
    c0v = (s0 + s1) + (s2 + s3);
    b1v = b1[t];
    rh_[t] = 0.f;
  }
  const float b2v0 = b2[t];
  const float b2v1 = b2[t + 512];
  float o0 = 0.f, mo0 = 0.f, vo0 = 0.f;
  float o1 = 0.f, mo1 = 0.f, vo1 = 0.f;
  ro_[t] = 0.f;
  ro_[t + 512] = 0.f;
  const int niter = *niterp;
  float pw1 = 1.f, pw2 = 1.f;
  __syncthreads();

  for (int it = 1; it <= niter; ++it) {
    pw1 *= 0.9f;
    pw2 *= 0.999f;
    const float bc1 = 1.f - pw1, bc2 = 1.f - pw2;
    // rh for own 8 rows -> regs
    float rh8[8];
    {
      const float4 ra = *reinterpret_cast<const float4*>(&rh_[8 * rr]);
      const float4 rb = *reinterpret_cast<const float4*>(&rh_[8 * rr + 4]);
      rh8[0] = ra.x; rh8[1] = ra.y; rh8[2] = ra.z; rh8[3] = ra.w;
      rh8[4] = rb.x; rh8[5] = rb.y; rh8[6] = rb.z; rh8[7] = rb.w;
    }
    float pa[8] = {0.f, 0.f, 0.f, 0.f, 0.f, 0.f, 0.f, 0.f};
    // ---- fused pass, reg cols (two 12-col sub-passes to cap live VGPRs) ----
#pragma unroll
    for (int sp = 0; sp < 2; ++sp) {
      float bacc[12] = {0.f, 0.f, 0.f, 0.f, 0.f, 0.f,
                        0.f, 0.f, 0.f, 0.f, 0.f, 0.f};
#pragma unroll
      for (int i4 = 0; i4 < 3; ++i4) {
        const float4 r4 =
            *reinterpret_cast<const float4*>(&ro_[RC + sp * 12 + i4 * 4]);
#pragma unroll
        for (int q = 0; q < 4; ++q) {
          const float roc = (&r4.x)[q];
          const int c = sp * 12 + i4 * 4 + q;
#pragma unroll
          for (int r = 0; r < 8; ++r) {
            const float we = w[r * 24 + c];
            bacc[i4 * 4 + q] = fmaf(rh8[r], we, bacc[i4 * 4 + q]);
            pa[r] = fmaf(we, roc, pa[r]);
          }
        }
      }
#pragma unroll
      for (int c = 0; c < 12; ++c) bacc[c] = dpp_reduce16(bacc[c]);
      if (rr == 15) {  // row_shr chain: complete 16-sum lives in lane 15
#pragma unroll
        for (int i4 = 0; i4 < 3; ++i4)
          *reinterpret_cast<float4*>(&bl_[RC + sp * 12 + i4 * 4]) =
              make_float4(bacc[i4 * 4], bacc[i4 * 4 + 1], bacc[i4 * 4 + 2],
                          bacc[i4 * 4 + 3]);
      }
    }
    // ---- fused pass, LDS cols (8) ----
    {
      float bacc[8] = {0.f, 0.f, 0.f, 0.f, 0.f, 0.f, 0.f, 0.f};
      const float4 r4a = *reinterpret_cast<const float4*>(&ro_[LC]);
      const float4 r4b = *reinterpret_cast<const float4*>(&ro_[LC + 4]);
#pragma unroll
      for (int c = 0; c < 8; ++c) {
        const int s = c * 32 + cg;
        const float4* wc = reinterpret_cast<const float4*>(&wlds[s * 128]);
        const int sw = s & 7;
        const float4 wa = wc[(2 * rr) ^ sw];       // rows 8rr..+4
        const float4 wb = wc[(2 * rr + 1) ^ sw];   // rows 8rr+4..+8
        const float roc = (c < 4) ? (&r4a.x)[c] : (&r4b.x)[c - 4];
        bacc[c] = fmaf(rh8[0], wa.x, bacc[c]);
        bacc[c] = fmaf(rh8[1], wa.y, bacc[c]);
        bacc[c] = fmaf(rh8[2], wa.z, bacc[c]);
        bacc[c] = fmaf(rh8[3], wa.w, bacc[c]);
        bacc[c] = fmaf(rh8[4], wb.x, bacc[c]);
        bacc[c] = fmaf(rh8[5], wb.y, bacc[c]);
        bacc[c] = fmaf(rh8[6], wb.z, bacc[c]);
        bacc[c] = fmaf(rh8[7], wb.w, bacc[c]);
        pa[0] = fmaf(wa.x, roc, pa[0]);
        pa[1] = fmaf(wa.y, roc, pa[1]);
        pa[2] = fmaf(wa.z, roc, pa[2]);
        pa[3] = fmaf(wa.w, roc, pa[3]);
        pa[4] = fmaf(wb.x, roc, pa[4]);
        pa[5] = fmaf(wb.y, roc, pa[5]);
        pa[6] = fmaf(wb.z, roc, pa[6]);
        pa[7] = fmaf(wb.w, roc, pa[7]);
      }
#pragma unroll
      for (int c = 0; c < 8; ++c) bacc[c] = dpp_reduce16(bacc[c]);
      if (rr == 15) {  // complete sum in lane 15 (see dpp_reduce16)
        *reinterpret_cast<float4*>(&bl_[LC]) =
            make_float4(bacc[0], bacc[1], bacc[2], bacc[3]);
        *reinterpret_cast<float4*>(&bl_[LC + 4]) =
            make_float4(bacc[4], bacc[5], bacc[6], bacc[7]);
      }
    }
    // ---- stage a-partials ----
    *reinterpret_cast<float4*>(&ap_[cg][8 * rr]) =
        make_float4(pa[0], pa[1], pa[2], pa[3]);
    *reinterpret_cast<float4*>(&ap_[cg][8 * rr + 4]) =
        make_float4(pa[4], pa[5], pa[6], pa[7]);
    __syncthreads();  // pass complete: bl_/ap_ valid; ro_/rh_ free to rewrite
    // ---- o-update: thread owns cols t and t+512 ----
    {
      const float bs0 = bl_[t], bs1 = bl_[t + 512];
      const float r0o = rho(o0), r1o = rho(o1);
      float go = drho(o0) * (r0o - b2v0 - bs0);
      mo0 = 0.9f * mo0 + 0.1f * go;
      vo0 = 0.999f * vo0 + 0.001f * (go * go);
      o0 -= 0.01f * (mo0 / bc1) / (sqrtf(vo0 / bc2) + 1e-8f);
      go = drho(o1) * (r1o - b2v1 - bs1);
      mo1 = 0.9f * mo1 + 0.1f * go;
      vo1 = 0.999f * vo1 + 0.001f * (go * go);
      o1 -= 0.01f * (mo1 / bc1) / (sqrtf(vo1 / bc2) + 1e-8f);
      ro_[t] = rho(o0);
      ro_[t + 512] = rho(o1);
    }
    // ---- h-update: thread t<128 owns row t ----
    if (t < 128) {
      float a0 = 0.f, a1 = 0.f, a2 = 0.f, a3 = 0.f;
#pragma unroll
      for (int q = 0; q < 32; q += 4) {
        a0 += ap_[q + 0][t];
        a1 += ap_[q + 1][t];
        a2 += ap_[q + 2][t];
        a3 += ap_[q + 3][t];
      }
      const float a = (a0 + a1) + (a2 + a3);
      const float rold = rho(hreg);
      const float gh = drho(hreg) * (rold - b1v - c0v - a);
      mh = 0.9f * mh + 0.1f * gh;
      vh = 0.999f * vh + 0.001f * (gh * gh);
      hreg -= 0.01f * (mh / bc1) / (sqrtf(vh / bc2) + 1e-8f);
      rh_[t] = rho(hreg);
    }
    __syncthreads();  // rh_/ro_ updated for next pass
  }
  out[t] = o0;
  out[t + 512] = o1;
}

extern "C" void kernel_launch(void* const* d_in, const int* in_sizes, int n_in,
                              void* d_out, int out_size, void* d_ws,
                              size_t ws_size, hipStream_t stream) {
  const float* x  = (const float*)d_in[0];
  // d_in[1] = b0: constant in E w.r.t. (h,o) -> never needed
  const float* b1 = (const float*)d_in[2];
  const float* b2 = (const float*)d_in[3];
  const float* W0 = (const float*)d_in[4];
  const float* W1 = (const float*)d_in[5];
  const int*   ni = (const int*)d_in[6];
  float* out = (float*)d_out;

  char* ws = (char*)d_ws;
  float* part2 = (float*)ws;             // <=32 x 128 f32 = 16 KB
  float* part1 = (float*)(ws + 16384);

  const int nrows = in_sizes[0];  // 262144
  const size_t hdr = 16384;
  int nblk1;
  if (ws_size >= hdr + (size_t)(nrows / 256) * 512) {
    nblk1 = nrows / 256;  // 1024 blocks
    hipLaunchKernelGGL(k1_xw0<256>, dim3(nblk1), dim3(256), 0, stream,
                       x, W0, part1);
  } else if (ws_size >= hdr + (size_t)(nrows / 512) * 512) {
    nblk1 = nrows / 512;
    hipLaunchKernelGGL(k1_xw0<512>, dim3(nblk1), dim3(256), 0, stream,
                       x, W0, part1);
  } else {
    nblk1 = nrows / 1024;
    hipLaunchKernelGGL(k1_xw0<1024>, dim3(nblk1), dim3(256), 0, stream,
                       x, W0, part1);
  }
  const int nblk2 = nblk1 / 32;
  hipLaunchKernelGGL(k1b_reduce, dim3(nblk2), dim3(256), 0, stream,
                     part1, part2);
  hipLaunchKernelGGL(k2_iter, dim3(1), dim3(512), 0, stream,
                     part2, nblk2, W1, b1, b2, ni, out);
}

// Round 9
// 419.514 us; speedup vs baseline: 1.0019x; 1.0019x over previous
//
#include <hip/hip_runtime.h>
#include <math.h>

__device__ __forceinline__ float rho(float s) { return fminf(fmaxf(s, 0.f), 1.f); }
// d/ds clip(s,0,1) with JAX maximum/minimum tie-gradient = 0.5
__device__ __forceinline__ float drho(float s) {
  if (s < 0.f || s > 1.f) return 0.f;
  float g = 1.f;
  if (s == 0.f) g *= 0.5f;
  if (s == 1.f) g *= 0.5f;
  return g;
}

// v += CTRL-shifted v within 16-lane DPP row; bound_ctrl -> 0 fill.
// row_shr moves data toward HIGHER lanes: complete 16-sum lands in lane 15.
template <int CTRL>
__device__ __forceinline__ float dpp_add(float v) {
  const int x =
      __builtin_amdgcn_update_dpp(0, __float_as_int(v), CTRL, 0xf, 0xf, true);
  return v + __int_as_float(x);
}
__device__ __forceinline__ float dpp_reduce16(float v) {
  v = dpp_add<0x118>(v);  // row_shr:8
  v = dpp_add<0x114>(v);  // row_shr:4
  v = dpp_add<0x112>(v);  // row_shr:2
  v = dpp_add<0x111>(v);  // row_shr:1  -> lane rr==15 holds the 16-sum
  return v;
}

// ---------------- Phase A: per-block partials of c0 = rho(x) @ W0 ----------
template <int ROWS>
__global__ __launch_bounds__(256) void k1_xw0(const float* __restrict__ x,
                                              const float* __restrict__ W0,
                                              float* __restrict__ part) {
  __shared__ float xs[ROWS];
  __shared__ float red[8][132];
  const int t = threadIdx.x;
  const int b = blockIdx.x;
  const int r0 = b * ROWS;
  for (int i = t; i < ROWS; i += 256) xs[i] = rho(x[r0 + i]);
  __syncthreads();
  const int cq = t & 31;
  const int rg = t >> 5;
  constexpr int GR = ROWS / 8;
  const float4* __restrict__ W4 = reinterpret_cast<const float4*>(W0);
  float ax = 0.f, ay = 0.f, az = 0.f, aw = 0.f;
  const int base = (r0 + rg * GR) * 32 + cq;
#pragma unroll 8
  for (int i = 0; i < GR; ++i) {
    const float xv = xs[rg * GR + i];
    const float4 w = W4[base + i * 32];
    ax = fmaf(xv, w.x, ax);
    ay = fmaf(xv, w.y, ay);
    az = fmaf(xv, w.z, az);
    aw = fmaf(xv, w.w, aw);
  }
  red[rg][cq * 4 + 0] = ax;
  red[rg][cq * 4 + 1] = ay;
  red[rg][cq * 4 + 2] = az;
  red[rg][cq * 4 + 3] = aw;
  __syncthreads();
  if (t < 128) {
    float s = 0.f;
#pragma unroll
    for (int g = 0; g < 8; ++g) s += red[g][t];
    part[b * 128 + t] = s;
  }
}

// ---------------- Phase A2: tree-reduce part1 (nblk x 128) -> part2 --------
__global__ __launch_bounds__(256) void k1b_reduce(const float* __restrict__ part1,
                                                  float* __restrict__ part2) {
  __shared__ float acc[2][128];
  const int t = threadIdx.x, i = blockIdx.x;
  const int jk = t & 127, half = t >> 7;
  float s = 0.f;
  const int r0 = i * 32 + half * 16;
#pragma unroll
  for (int r = 0; r < 16; ++r) s += part1[(r0 + r) * 128 + jk];
  acc[half][jk] = s;
  __syncthreads();
  if (half == 0) part2[i * 128 + jk] = acc[0][jk] + acc[1][jk];
}

// ---------------- Phase B: ONE workgroup, W1 resident on a single CU --------
// 512 threads = 8 waves = 2 waves/SIMD. waves_per_eu(1,2): VGPR cap 512 ->
// the 192-float W-tile stays in registers (r8 failure: launch_bounds(512,2)
// capped VGPR at 128 and spilled the tile to scratch -> 420 us).
__global__ __attribute__((amdgpu_flat_work_group_size(512, 512),
                          amdgpu_waves_per_eu(1, 2)))
void k2_iter(const float* __restrict__ part2,
             const int npart2,
             const float* __restrict__ W1,
             const float* __restrict__ b1,
             const float* __restrict__ b2,
             const int* __restrict__ niterp,
             float* __restrict__ out) {
  __shared__ float wlds[256 * 128];  // 128 KB: cols 768..1023, swizzled
  __shared__ float ro_[1024];
  __shared__ float rh_[128];
  __shared__ float bl_[1024];
  __shared__ float ap_[32][132];     // a-partials per col-group

  const int t = threadIdx.x;
  const int lane = t & 63;
  const int wv = t >> 6;
  const int rr = lane & 15;        // row group: rows [8rr, 8rr+8)
  const int cg = wv * 4 + (lane >> 4);  // col group in [0,32)
  const int RC = cg * 24;          // reg-col base (global col)
  const int LC = 768 + cg * 8;     // lds-col base (global col)

  // ---- load reg tile W[8rr..+8][RC..RC+24) : 192 VGPRs, static-indexed ----
  float w[192];
#pragma unroll
  for (int r = 0; r < 8; ++r) {
    const float4* gr =
        reinterpret_cast<const float4*>(W1 + (8 * rr + r) * 1024 + RC);
#pragma unroll
    for (int i = 0; i < 6; ++i) {
      const float4 v = gr[i];
      w[r * 24 + 4 * i + 0] = v.x;
      w[r * 24 + 4 * i + 1] = v.y;
      w[r * 24 + 4 * i + 2] = v.z;
      w[r * 24 + 4 * i + 3] = v.w;
    }
  }
  // ---- load cols 768..1023 into LDS, slot-permuted + row4-XOR swizzled ----
  // col k (local [0,256)) -> slot s = (k&7)*32 + (k>>3); element (j,k) at
  // wlds[s*128 + ((j>>2 ^ (s&7))<<2) + (j&3)]  (conflict-free tile reads)
  {
    const int j = t >> 2;
    const int kb = (t & 3) * 64;
#pragma unroll
    for (int i = 0; i < 16; ++i) {
      const float4 v =
          *reinterpret_cast<const float4*>(W1 + j * 1024 + 768 + kb + 4 * i);
#pragma unroll
      for (int q = 0; q < 4; ++q) {
        const int K = kb + 4 * i + q;
        const int s = (K & 7) * 32 + (K >> 3);
        wlds[s * 128 + (((j >> 2) ^ (s & 7)) << 2) + (j & 3)] = (&v.x)[q];
      }
    }
  }
  // ---- init: c0 (rows, t<128), biases, zero state ----
  float c0v = 0.f, b1v = 0.f, hreg = 0.f, mh = 0.f, vh = 0.f;
  if (t < 128) {
    float s0 = 0.f, s1 = 0.f, s2 = 0.f, s3 = 0.f;
    for (int r = 0; r < npart2; r += 4) {
      s0 += part2[(r + 0) * 128 + t];
      s1 += part2[(r + 1) * 128 + t];
      s2 += part2[(r + 2) * 128 + t];
      s3 += part2[(r + 3) * 128 + t];
    }
    c0v = (s0 + s1) + (s2 + s3);
    b1v = b1[t];
    rh_[t] = 0.f;
  }
  const float b2v0 = b2[t];
  const float b2v1 = b2[t + 512];
  float o0 = 0.f, mo0 = 0.f, vo0 = 0.f;
  float o1 = 0.f, mo1 = 0.f, vo1 = 0.f;
  ro_[t] = 0.f;
  ro_[t + 512] = 0.f;
  const int niter = *niterp;
  float pw1 = 1.f, pw2 = 1.f;
  __syncthreads();

  for (int it = 1; it <= niter; ++it) {
    pw1 *= 0.9f;
    pw2 *= 0.999f;
    const float bc1 = 1.f - pw1, bc2 = 1.f - pw2;
    // rh for own 8 rows -> regs
    float rh8[8];
    {
      const float4 ra = *reinterpret_cast<const float4*>(&rh_[8 * rr]);
      const float4 rb = *reinterpret_cast<const float4*>(&rh_[8 * rr + 4]);
      rh8[0] = ra.x; rh8[1] = ra.y; rh8[2] = ra.z; rh8[3] = ra.w;
      rh8[4] = rb.x; rh8[5] = rb.y; rh8[6] = rb.z; rh8[7] = rb.w;
    }
    float pa[8] = {0.f, 0.f, 0.f, 0.f, 0.f, 0.f, 0.f, 0.f};
    // ---- fused pass, reg cols (two 12-col sub-passes to cap live VGPRs) ----
#pragma unroll
    for (int sp = 0; sp < 2; ++sp) {
      float bacc[12] = {0.f, 0.f, 0.f, 0.f, 0.f, 0.f,
                        0.f, 0.f, 0.f, 0.f, 0.f, 0.f};
#pragma unroll
      for (int i4 = 0; i4 < 3; ++i4) {
        const float4 r4 =
            *reinterpret_cast<const float4*>(&ro_[RC + sp * 12 + i4 * 4]);
#pragma unroll
        for (int q = 0; q < 4; ++q) {
          const float roc = (&r4.x)[q];
          const int c = sp * 12 + i4 * 4 + q;
#pragma unroll
          for (int r = 0; r < 8; ++r) {
            const float we = w[r * 24 + c];
            bacc[i4 * 4 + q] = fmaf(rh8[r], we, bacc[i4 * 4 + q]);
            pa[r] = fmaf(we, roc, pa[r]);
          }
        }
      }
#pragma unroll
      for (int c = 0; c < 12; ++c) bacc[c] = dpp_reduce16(bacc[c]);
      if (rr == 15) {  // row_shr chain: complete 16-sum lives in lane 15
#pragma unroll
        for (int i4 = 0; i4 < 3; ++i4)
          *reinterpret_cast<float4*>(&bl_[RC + sp * 12 + i4 * 4]) =
              make_float4(bacc[i4 * 4], bacc[i4 * 4 + 1], bacc[i4 * 4 + 2],
                          bacc[i4 * 4 + 3]);
      }
    }
    // ---- fused pass, LDS cols (8) ----
    {
      float bacc[8] = {0.f, 0.f, 0.f, 0.f, 0.f, 0.f, 0.f, 0.f};
      const float4 r4a = *reinterpret_cast<const float4*>(&ro_[LC]);
      const float4 r4b = *reinterpret_cast<const float4*>(&ro_[LC + 4]);
#pragma unroll
      for (int c = 0; c < 8; ++c) {
        const int s = c * 32 + cg;
        const float4* wc = reinterpret_cast<const float4*>(&wlds[s * 128]);
        const int sw = s & 7;
        const float4 wa = wc[(2 * rr) ^ sw];       // rows 8rr..+4
        const float4 wb = wc[(2 * rr + 1) ^ sw];   // rows 8rr+4..+8
        const float roc = (c < 4) ? (&r4a.x)[c] : (&r4b.x)[c - 4];
        bacc[c] = fmaf(rh8[0], wa.x, bacc[c]);
        bacc[c] = fmaf(rh8[1], wa.y, bacc[c]);
        bacc[c] = fmaf(rh8[2], wa.z, bacc[c]);
        bacc[c] = fmaf(rh8[3], wa.w, bacc[c]);
        bacc[c] = fmaf(rh8[4], wb.x, bacc[c]);
        bacc[c] = fmaf(rh8[5], wb.y, bacc[c]);
        bacc[c] = fmaf(rh8[6], wb.z, bacc[c]);
        bacc[c] = fmaf(rh8[7], wb.w, bacc[c]);
        pa[0] = fmaf(wa.x, roc, pa[0]);
        pa[1] = fmaf(wa.y, roc, pa[1]);
        pa[2] = fmaf(wa.z, roc, pa[2]);
        pa[3] = fmaf(wa.w, roc, pa[3]);
        pa[4] = fmaf(wb.x, roc, pa[4]);
        pa[5] = fmaf(wb.y, roc, pa[5]);
        pa[6] = fmaf(wb.z, roc, pa[6]);
        pa[7] = fmaf(wb.w, roc, pa[7]);
      }
#pragma unroll
      for (int c = 0; c < 8; ++c) bacc[c] = dpp_reduce16(bacc[c]);
      if (rr == 15) {  // complete sum in lane 15 (see dpp_reduce16)
        *reinterpret_cast<float4*>(&bl_[LC]) =
            make_float4(bacc[0], bacc[1], bacc[2], bacc[3]);
        *reinterpret_cast<float4*>(&bl_[LC + 4]) =
            make_float4(bacc[4], bacc[5], bacc[6], bacc[7]);
      }
    }
    // ---- stage a-partials ----
    *reinterpret_cast<float4*>(&ap_[cg][8 * rr]) =
        make_float4(pa[0], pa[1], pa[2], pa[3]);
    *reinterpret_cast<float4*>(&ap_[cg][8 * rr + 4]) =
        make_float4(pa[4], pa[5], pa[6], pa[7]);
    __syncthreads();  // pass complete: bl_/ap_ valid; ro_/rh_ free to rewrite
    // ---- o-update: thread owns cols t and t+512 ----
    {
      const float bs0 = bl_[t], bs1 = bl_[t + 512];
      const float r0o = rho(o0), r1o = rho(o1);
      float go = drho(o0) * (r0o - b2v0 - bs0);
      mo0 = 0.9f * mo0 + 0.1f * go;
      vo0 = 0.999f * vo0 + 0.001f * (go * go);
      o0 -= 0.01f * (mo0 / bc1) / (sqrtf(vo0 / bc2) + 1e-8f);
      go = drho(o1) * (r1o - b2v1 - bs1);
      mo1 = 0.9f * mo1 + 0.1f * go;
      vo1 = 0.999f * vo1 + 0.001f * (go * go);
      o1 -= 0.01f * (mo1 / bc1) / (sqrtf(vo1 / bc2) + 1e-8f);
      ro_[t] = rho(o0);
      ro_[t + 512] = rho(o1);
    }
    // ---- h-update: thread t<128 owns row t ----
    if (t < 128) {
      float a0 = 0.f, a1 = 0.f, a2 = 0.f, a3 = 0.f;
#pragma unroll
      for (int q = 0; q < 32; q += 4) {
        a0 += ap_[q + 0][t];
        a1 += ap_[q + 1][t];
        a2 += ap_[q + 2][t];
        a3 += ap_[q + 3][t];
      }
      const float a = (a0 + a1) + (a2 + a3);
      const float rold = rho(hreg);
      const float gh = drho(hreg) * (rold - b1v - c0v - a);
      mh = 0.9f * mh + 0.1f * gh;
      vh = 0.999f * vh + 0.001f * (gh * gh);
      hreg -= 0.01f * (mh / bc1) / (sqrtf(vh / bc2) + 1e-8f);
      rh_[t] = rho(hreg);
    }
    __syncthreads();  // rh_/ro_ updated for next pass
  }
  out[t] = o0;
  out[t + 512] = o1;
}

extern "C" void kernel_launch(void* const* d_in, const int* in_sizes, int n_in,
                              void* d_out, int out_size, void* d_ws,
                              size_t ws_size, hipStream_t stream) {
  const float* x  = (const float*)d_in[0];
  // d_in[1] = b0: constant in E w.r.t. (h,o) -> never needed
  const float* b1 = (const float*)d_in[2];
  const float* b2 = (const float*)d_in[3];
  const float* W0 = (const float*)d_in[4];
  const float* W1 = (const float*)d_in[5];
  const int*   ni = (const int*)d_in[6];
  float* out = (float*)d_out;

  char* ws = (char*)d_ws;
  float* part2 = (float*)ws;             // <=32 x 128 f32 = 16 KB
  float* part1 = (float*)(ws + 16384);

  const int nrows = in_sizes[0];  // 262144
  const size_t hdr = 16384;
  int nblk1;
  if (ws_size >= hdr + (size_t)(nrows / 256) * 512) {
    nblk1 = nrows / 256;  // 1024 blocks
    hipLaunchKernelGGL(k1_xw0<256>, dim3(nblk1), dim3(256), 0, stream,
                       x, W0, part1);
  } else if (ws_size >= hdr + (size_t)(nrows / 512) * 512) {
    nblk1 = nrows / 512;
    hipLaunchKernelGGL(k1_xw0<512>, dim3(nblk1), dim3(256), 0, stream,
                       x, W0, part1);
  } else {
    nblk1 = nrows / 1024;
    hipLaunchKernelGGL(k1_xw0<1024>, dim3(nblk1), dim3(256), 0, stream,
                       x, W0, part1);
  }
  const int nblk2 = nblk1 / 32;
  hipLaunchKernelGGL(k1b_reduce, dim3(nblk2), dim3(256), 0, stream,
                     part1, part2);
  hipLaunchKernelGGL(k2_iter, dim3(1), dim3(512), 0, stream,
                     part2, nblk2, W1, b1, b2, ni, out);
}